// Round 1
// 134.192 us; speedup vs baseline: 1.1612x; 1.1612x over previous
//
#include <hip/hip_runtime.h>

// Problem constants: N=B*T=65536, D=256, K=1024
#define NTOT 65536
#define DDIM 256
#define KCB  1024
#define ND   16777216   // NTOT * DDIM

typedef __attribute__((ext_vector_type(4))) float f32x4;
typedef __attribute__((ext_vector_type(4))) int   i32x4;
typedef __attribute__((ext_vector_type(4))) unsigned u32x4;
typedef __attribute__((ext_vector_type(2))) long long i64x2;

__device__ static inline unsigned umax32(unsigned a, unsigned b) { return a > b ? a : b; }

// ---- fp32 -> fp8 e4m3fn (OCP), 4-at-a-time pack into an int (byte i = x_i) --
#if !__has_builtin(__builtin_amdgcn_cvt_pk_fp8_f32)
__device__ static inline unsigned f32_to_e4m3_1(float f) {
    unsigned u = __float_as_uint(f);
    unsigned s = (u >> 24) & 0x80u;
    unsigned a = u & 0x7fffffffu;
    float x = __uint_as_float(a);
    if (x >= 448.f) return s | 0x7Eu;
    if (x < 0.015625f) {                    // subnormal: multiples of 2^-9
        int m = (int)__builtin_rintf(x * 512.f);   // RNE, 0..8
        return s | (unsigned)m;             // m==8 -> 0x08 == 2^-6 normal, correct
    }
    unsigned r = (a + 0x7FFFFu + ((a >> 20) & 1u)) >> 20;   // RNE to 3 mantissa bits
    int E = (int)(r >> 3) - 127;
    unsigned code = ((unsigned)(E + 7) << 3) | (r & 7u);
    if (code >= 0x7Fu) code = 0x7Eu;
    return s | code;
}
#endif

__device__ static inline int pk4_fp8(float x0, float x1, float x2, float x3) {
#if __has_builtin(__builtin_amdgcn_cvt_pk_fp8_f32)
    int w = __builtin_amdgcn_cvt_pk_fp8_f32(x0, x1, 0, false);   // bytes 0,1
    w = __builtin_amdgcn_cvt_pk_fp8_f32(x2, x3, w, true);        // bytes 2,3
    return w;
#else
    return (int)(f32_to_e4m3_1(x0) | (f32_to_e4m3_1(x1) << 8) |
                 (f32_to_e4m3_1(x2) << 16) | (f32_to_e4m3_1(x3) << 24));
#endif
}

// ---------------- Prep: codebook -> fp8(x512) fragments + 256*||e||^2 --------
// UNCHANGED layout. Fragment byte layout: frag (chunk cc = c>>4, ks = d>>5)
// holds lane (q*16 + c&15) bytes for k = ks*32 + q*8 + j. Pairs of ks share a
// 16B slot: addr = ((cc*4 + ks/2)*64 + lane)*16 + (ks&1)*8.
__global__ __launch_bounds__(256) void vq_prep_kernel(const float* __restrict__ cb,
                                                      char* __restrict__ cbf,
                                                      float* __restrict__ esq_scaled,
                                                      float* __restrict__ loss_out) {
    int gid = blockIdx.x * 256 + threadIdx.x;   // 0..32767
    int c = gid >> 5;
    int j8 = gid & 31;
    const float* p = cb + (size_t)c * DDIM + j8 * 8;
    f32x4 x = *(const f32x4*)p;
    f32x4 y = *(const f32x4*)(p + 4);
    float ss = x[0]*x[0] + x[1]*x[1] + x[2]*x[2] + x[3]*x[3]
             + y[0]*y[0] + y[1]*y[1] + y[2]*y[2] + y[3]*y[3];
    #pragma unroll
    for (int m = 16; m; m >>= 1) ss += __shfl_xor(ss, m);   // reduce the 32 lanes of code c
    if (j8 == 0) esq_scaled[c] = 256.f * ss;                // 512 * 0.5 * ||e||^2
    int w0 = pk4_fp8(512.f * x[0], 512.f * x[1], 512.f * x[2], 512.f * x[3]);
    int w1 = pk4_fp8(512.f * y[0], 512.f * y[1], 512.f * y[2], 512.f * y[3]);
    int ks = j8 >> 2, qq = j8 & 3;
    int cc = c >> 4, kp = ks >> 1, h = ks & 1;
    int lane2 = qq * 16 + (c & 15);
    size_t addr = ((size_t)(cc * 4 + kp) * 64 + lane2) * 16 + h * 8;
    *(long long*)(cbf + addr) = (long long)(unsigned)w0 | ((long long)w1 << 32);
    if (gid == 0) loss_out[0] = 0.f;
}

// ---------------- Main: 64 rows/block, wave = 64 rows x 256 cols -------------
// 1024 blocks x 256 thr (4 waves, cg = wave = col group of 256). z loaded ONCE
// per block, fp8-packed cooperatively, A-frags shared via 16KB LDS. Per 16-col
// chunk: 32 MFMA per 64B/lane of B (4x the old compute per L2 access; B L2
// traffic halved to 256 MB). Argmin via packed keys: acc init = 64-256||e||^2
// so final acc = s+64 > 0; key = (as_uint & ~1023) | (1023-col); all reduction
// levels are plain unsigned max with exact lowest-index tie-break.
__global__ __launch_bounds__(256, 3) void vq_main_kernel(const float* __restrict__ z,
                                                         const float* __restrict__ cb,
                                                         const char* __restrict__ cbf,
                                                         const float* __restrict__ esq_scaled,
                                                         float* __restrict__ out) {
    __shared__ long long A_lds[2048];   // 16 KB: frag (rf*8+ks)*64 + lane
    __shared__ float esq_s[KCB];        // 4 KB: 64 - 256*||e||^2
    __shared__ float zsq_s[64];
    __shared__ unsigned ur_s[256];      // [cg][row] packed keys
    __shared__ int idx_s[64];

    const int tid  = threadIdx.x;
    const int cg   = tid >> 6;          // wave id = column group (cols cg*256..)
    const int lane = tid & 63;
    const int q    = lane >> 4;
    const int ln   = lane & 15;
    const int b0   = blockIdx.x * 64;

    #pragma unroll
    for (int i = 0; i < 4; ++i) {
        int ix = tid + i * 256;
        esq_s[ix] = 64.0f - esq_scaled[ix];   // bias +64 folded in, negated
    }

    // early B prefetch for chunk 0 (L2 hit, lands during the z-load phase)
    const char* bbase = cbf + (size_t)cg * 65536 + lane * 16;
    i32x4 B0[4], B1[4];
    #pragma unroll
    for (int kp = 0; kp < 4; ++kp)
        B0[kp] = *(const i32x4*)(bbase + kp * 1024);

    // ---- cooperative A load/pack: thread (r=tid>>2, t=tid&3) owns 64 floats -
    {
        const int r = tid >> 2, t = tid & 3;
        const int rf = r >> 4, mm = r & 15;
        const float* zp = z + (size_t)(b0 + r) * DDIM + t * 64;
        float sq = 0.f;
        #pragma unroll
        for (int s = 0; s < 2; ++s) {           // ks = 2t + s
            #pragma unroll
            for (int qq = 0; qq < 4; ++qq) {
                f32x4 x = *(const f32x4*)(zp + s * 32 + qq * 8);
                f32x4 y = *(const f32x4*)(zp + s * 32 + qq * 8 + 4);
                sq += x[0]*x[0] + x[1]*x[1] + x[2]*x[2] + x[3]*x[3]
                    + y[0]*y[0] + y[1]*y[1] + y[2]*y[2] + y[3]*y[3];
                int w0 = pk4_fp8(x[0], x[1], x[2], x[3]);
                int w1 = pk4_fp8(y[0], y[1], y[2], y[3]);
                A_lds[(rf * 8 + 2 * t + s) * 64 + qq * 16 + mm] =
                    (long long)(unsigned)w0 | ((long long)w1 << 32);
            }
        }
        sq += __shfl_xor(sq, 1);
        sq += __shfl_xor(sq, 2);                // row sum over the 4 t-lanes
        if (t == 0) zsq_s[r] = sq;
    }
    __syncthreads();

    // ---- A frags to regs: 32 x ds_read_b64, lane-contiguous (conflict-free) -
    long long a[4][8];
    #pragma unroll
    for (int rf = 0; rf < 4; ++rf)
        #pragma unroll
        for (int ks = 0; ks < 8; ++ks)
            a[rf][ks] = A_lds[(rf * 8 + ks) * 64 + lane];

    unsigned best[16];
    #pragma unroll
    for (int i = 0; i < 16; ++i) best[i] = 0u;

    const float* ep = esq_s + cg * 256 + ln;
    const int colinv0 = 1023 - cg * 256 - ln;

    // ---- K-loop: 16 chunks of 16 cols, ping-pong prefetch, no barriers ------
#define VQ_STEP(Bc_, Bn_, C_, CN_)                                             \
    {                                                                          \
        _Pragma("unroll")                                                      \
        for (int kp = 0; kp < 4; ++kp)                                         \
            Bn_[kp] = *(const i32x4*)(bbase + (size_t)((CN_) * 4 + kp) * 1024);\
        const float e4 = ep[(C_) * 16];                                        \
        f32x4 ac0 = {e4, e4, e4, e4};                                          \
        f32x4 ac1 = ac0, ac2 = ac0, ac3 = ac0;                                 \
        _Pragma("unroll")                                                      \
        for (int kp = 0; kp < 4; ++kp) {                                       \
            i64x2 pr = __builtin_bit_cast(i64x2, Bc_[kp]);                     \
            ac0 = __builtin_amdgcn_mfma_f32_16x16x32_fp8_fp8(a[0][2*kp],   pr[0], ac0, 0, 0, 0); \
            ac1 = __builtin_amdgcn_mfma_f32_16x16x32_fp8_fp8(a[1][2*kp],   pr[0], ac1, 0, 0, 0); \
            ac2 = __builtin_amdgcn_mfma_f32_16x16x32_fp8_fp8(a[2][2*kp],   pr[0], ac2, 0, 0, 0); \
            ac3 = __builtin_amdgcn_mfma_f32_16x16x32_fp8_fp8(a[3][2*kp],   pr[0], ac3, 0, 0, 0); \
            ac0 = __builtin_amdgcn_mfma_f32_16x16x32_fp8_fp8(a[0][2*kp+1], pr[1], ac0, 0, 0, 0); \
            ac1 = __builtin_amdgcn_mfma_f32_16x16x32_fp8_fp8(a[1][2*kp+1], pr[1], ac1, 0, 0, 0); \
            ac2 = __builtin_amdgcn_mfma_f32_16x16x32_fp8_fp8(a[2][2*kp+1], pr[1], ac2, 0, 0, 0); \
            ac3 = __builtin_amdgcn_mfma_f32_16x16x32_fp8_fp8(a[3][2*kp+1], pr[1], ac3, 0, 0, 0); \
        }                                                                      \
        const unsigned ci = (unsigned)(colinv0 - (C_) * 16);                   \
        _Pragma("unroll")                                                      \
        for (int i = 0; i < 4; ++i) {                                          \
            unsigned k0 = (__float_as_uint(ac0[i]) & 0xFFFFFC00u) | ci;        \
            unsigned k1 = (__float_as_uint(ac1[i]) & 0xFFFFFC00u) | ci;        \
            unsigned k2 = (__float_as_uint(ac2[i]) & 0xFFFFFC00u) | ci;        \
            unsigned k3 = (__float_as_uint(ac3[i]) & 0xFFFFFC00u) | ci;        \
            best[i]      = umax32(best[i],      k0);                           \
            best[4 + i]  = umax32(best[4 + i],  k1);                           \
            best[8 + i]  = umax32(best[8 + i],  k2);                           \
            best[12 + i] = umax32(best[12 + i], k3);                           \
        }                                                                      \
    }

    for (int c = 0; c < 16; c += 2) {
        VQ_STEP(B0, B1, c, c + 1);
        VQ_STEP(B1, B0, c + 1, (c + 2) & 15);   // wraps to 0: harmless re-read
    }
#undef VQ_STEP

    // ---- reduce over the 16 ln-lanes of each q-group (integer max only) ----
    #pragma unroll
    for (int m = 1; m < 16; m <<= 1)
        #pragma unroll
        for (int i = 0; i < 16; ++i)
            best[i] = umax32(best[i], (unsigned)__shfl_xor((int)best[i], m));

    if (ln == 0) {
        #pragma unroll
        for (int rf = 0; rf < 4; ++rf) {
            u32x4 v = {best[rf * 4 + 0], best[rf * 4 + 1],
                       best[rf * 4 + 2], best[rf * 4 + 3]};
            *(u32x4*)(ur_s + cg * 64 + rf * 16 + q * 4) = v;   // rows rf*16+q*4+i
        }
    }
    __syncthreads();

    if (tid < 64) {
        unsigned u = umax32(umax32(ur_s[tid], ur_s[64 + tid]),
                            umax32(ur_s[128 + tid], ur_s[192 + tid]));
        int k = 1023 - (int)(u & 1023u);
        // midpoint-reconstruct the truncated score: s+64
        float sval = __uint_as_float((u & 0xFFFFFC00u) | 0x200u) - 64.0f;
        idx_s[tid] = k;
        // row loss: ||z-e*||^2 = ||z||^2 - s/256
        float lsum = zsq_s[tid] - sval * 0.00390625f;
        #pragma unroll
        for (int off = 32; off; off >>= 1) lsum += __shfl_down(lsum, off);
        if (tid == 0) atomicAdd(out + ND, lsum * (1.0f / (float)ND));
    }
    __syncthreads();

    // ---- epilogue: float4 gather + non-temporal store (don't pollute L2) ---
    #pragma unroll
    for (int i = 0; i < 16; ++i) {
        int item = tid + i * 256;
        int row = item >> 6, c4 = item & 63;
        int k = idx_s[row];
        f32x4 v = *(const f32x4*)(cb + (size_t)k * DDIM + c4 * 4);
        __builtin_nontemporal_store(v, (f32x4*)(out + (size_t)(b0 + row) * DDIM + c4 * 4));
    }
}

extern "C" void kernel_launch(void* const* d_in, const int* in_sizes, int n_in,
                              void* d_out, int out_size, void* d_ws, size_t ws_size,
                              hipStream_t stream) {
    const float* z  = (const float*)d_in[0];   // z_e, 65536 x 256 fp32
    const float* cb = (const float*)d_in[1];   // codebook, 1024 x 256 fp32
    float* out = (float*)d_out;                // z_q (16777216) ++ loss (1)

    float* esq_scaled = (float*)d_ws;                    // 4 KB
    char*  cb_frag    = (char*)d_ws + 4096;              // 256 KB fp8 fragments

    vq_prep_kernel<<<128, 256, 0, stream>>>(cb, cb_frag, esq_scaled, out + ND);
    vq_main_kernel<<<NTOT / 64, 256, 0, stream>>>(z, cb, cb_frag, esq_scaled, out);
}

// Round 2
// 133.800 us; speedup vs baseline: 1.1646x; 1.0029x over previous
//
#include <hip/hip_runtime.h>

// Problem constants: N=B*T=65536, D=256, K=1024
#define NTOT 65536
#define DDIM 256
#define KCB  1024
#define ND   16777216   // NTOT * DDIM
#define NBLK 512        // main grid; block b does row-tiles b*64 and (b+512)*64

typedef __attribute__((ext_vector_type(4))) float f32x4;
typedef __attribute__((ext_vector_type(4))) int   i32x4;
typedef __attribute__((ext_vector_type(4))) unsigned u32x4;
typedef __attribute__((ext_vector_type(2))) long long i64x2;

__device__ static inline unsigned umax32(unsigned a, unsigned b) { return a > b ? a : b; }

// ---- fp32 -> fp8 e4m3fn (OCP), 4-at-a-time pack into an int (byte i = x_i) --
#if !__has_builtin(__builtin_amdgcn_cvt_pk_fp8_f32)
__device__ static inline unsigned f32_to_e4m3_1(float f) {
    unsigned u = __float_as_uint(f);
    unsigned s = (u >> 24) & 0x80u;
    unsigned a = u & 0x7fffffffu;
    float x = __uint_as_float(a);
    if (x >= 448.f) return s | 0x7Eu;
    if (x < 0.015625f) {                    // subnormal: multiples of 2^-9
        int m = (int)__builtin_rintf(x * 512.f);   // RNE, 0..8
        return s | (unsigned)m;             // m==8 -> 0x08 == 2^-6 normal, correct
    }
    unsigned r = (a + 0x7FFFFu + ((a >> 20) & 1u)) >> 20;   // RNE to 3 mantissa bits
    int E = (int)(r >> 3) - 127;
    unsigned code = ((unsigned)(E + 7) << 3) | (r & 7u);
    if (code >= 0x7Fu) code = 0x7Eu;
    return s | code;
}
#endif

__device__ static inline int pk4_fp8(float x0, float x1, float x2, float x3) {
#if __has_builtin(__builtin_amdgcn_cvt_pk_fp8_f32)
    int w = __builtin_amdgcn_cvt_pk_fp8_f32(x0, x1, 0, false);   // bytes 0,1
    w = __builtin_amdgcn_cvt_pk_fp8_f32(x2, x3, w, true);        // bytes 2,3
    return w;
#else
    return (int)(f32_to_e4m3_1(x0) | (f32_to_e4m3_1(x1) << 8) |
                 (f32_to_e4m3_1(x2) << 16) | (f32_to_e4m3_1(x3) << 24));
#endif
}

// ---------------- Prep: codebook -> fp8(x512) fragments + 256*||e||^2 --------
// UNCHANGED layout. Fragment byte layout: frag (chunk cc = c>>4, ks = d>>5)
// holds lane (q*16 + c&15) bytes for k = ks*32 + q*8 + j. Pairs of ks share a
// 16B slot: addr = ((cc*4 + ks/2)*64 + lane)*16 + (ks&1)*8.
__global__ __launch_bounds__(256) void vq_prep_kernel(const float* __restrict__ cb,
                                                      char* __restrict__ cbf,
                                                      float* __restrict__ esq_scaled,
                                                      float* __restrict__ loss_out) {
    int gid = blockIdx.x * 256 + threadIdx.x;   // 0..32767
    int c = gid >> 5;
    int j8 = gid & 31;
    const float* p = cb + (size_t)c * DDIM + j8 * 8;
    f32x4 x = *(const f32x4*)p;
    f32x4 y = *(const f32x4*)(p + 4);
    float ss = x[0]*x[0] + x[1]*x[1] + x[2]*x[2] + x[3]*x[3]
             + y[0]*y[0] + y[1]*y[1] + y[2]*y[2] + y[3]*y[3];
    #pragma unroll
    for (int m = 16; m; m >>= 1) ss += __shfl_xor(ss, m);   // reduce the 32 lanes of code c
    if (j8 == 0) esq_scaled[c] = 256.f * ss;                // 512 * 0.5 * ||e||^2
    int w0 = pk4_fp8(512.f * x[0], 512.f * x[1], 512.f * x[2], 512.f * x[3]);
    int w1 = pk4_fp8(512.f * y[0], 512.f * y[1], 512.f * y[2], 512.f * y[3]);
    int ks = j8 >> 2, qq = j8 & 3;
    int cc = c >> 4, kp = ks >> 1, h = ks & 1;
    int lane2 = qq * 16 + (c & 15);
    size_t addr = ((size_t)(cc * 4 + kp) * 64 + lane2) * 16 + h * 8;
    *(long long*)(cbf + addr) = (long long)(unsigned)w0 | ((long long)w1 << 32);
    if (gid == 0) loss_out[0] = 0.f;
}

// ---- pack 32 floats (8 f32x4) of one row-quarter into LDS frag f, slot mm ---
__device__ __forceinline__ float pack8(const f32x4* v, long long* A, int f, int mm) {
    float sq = 0.f;
    #pragma unroll
    for (int qq = 0; qq < 4; ++qq) {
        f32x4 x = v[2 * qq], y = v[2 * qq + 1];
        sq += x[0]*x[0] + x[1]*x[1] + x[2]*x[2] + x[3]*x[3]
            + y[0]*y[0] + y[1]*y[1] + y[2]*y[2] + y[3]*y[3];
        int w0 = pk4_fp8(x[0], x[1], x[2], x[3]);
        int w1 = pk4_fp8(y[0], y[1], y[2], y[3]);
        A[f * 64 + qq * 16 + mm] = (long long)(unsigned)w0 | ((long long)w1 << 32);
    }
    return sq;
}

// ---- one 16-col chunk: prefetch next B, 16 MFMA, packed-key argmin update ---
__device__ __forceinline__ void vq_step(const long long (&a)[4][8], unsigned (&best)[16],
                                        const char* bbase, const float* ep, int colinv0,
                                        i32x4 (&Bc)[4], i32x4 (&Bn)[4], int c, int cn) {
    #pragma unroll
    for (int kp = 0; kp < 4; ++kp)
        Bn[kp] = *(const i32x4*)(bbase + (size_t)(cn * 4 + kp) * 1024);
    const float e4 = ep[c * 16];
    f32x4 ac0 = {e4, e4, e4, e4};
    f32x4 ac1 = ac0, ac2 = ac0, ac3 = ac0;
    __builtin_amdgcn_s_setprio(1);
    #pragma unroll
    for (int kp = 0; kp < 4; ++kp) {
        i64x2 pr = __builtin_bit_cast(i64x2, Bc[kp]);
        ac0 = __builtin_amdgcn_mfma_f32_16x16x32_fp8_fp8(a[0][2*kp],   pr[0], ac0, 0, 0, 0);
        ac1 = __builtin_amdgcn_mfma_f32_16x16x32_fp8_fp8(a[1][2*kp],   pr[0], ac1, 0, 0, 0);
        ac2 = __builtin_amdgcn_mfma_f32_16x16x32_fp8_fp8(a[2][2*kp],   pr[0], ac2, 0, 0, 0);
        ac3 = __builtin_amdgcn_mfma_f32_16x16x32_fp8_fp8(a[3][2*kp],   pr[0], ac3, 0, 0, 0);
        ac0 = __builtin_amdgcn_mfma_f32_16x16x32_fp8_fp8(a[0][2*kp+1], pr[1], ac0, 0, 0, 0);
        ac1 = __builtin_amdgcn_mfma_f32_16x16x32_fp8_fp8(a[1][2*kp+1], pr[1], ac1, 0, 0, 0);
        ac2 = __builtin_amdgcn_mfma_f32_16x16x32_fp8_fp8(a[2][2*kp+1], pr[1], ac2, 0, 0, 0);
        ac3 = __builtin_amdgcn_mfma_f32_16x16x32_fp8_fp8(a[3][2*kp+1], pr[1], ac3, 0, 0, 0);
    }
    __builtin_amdgcn_s_setprio(0);
    const unsigned ci = (unsigned)(colinv0 - c * 16);
    #pragma unroll
    for (int i = 0; i < 4; ++i) {
        unsigned k0 = (__float_as_uint(ac0[i]) & 0xFFFFFC00u) | ci;
        unsigned k1 = (__float_as_uint(ac1[i]) & 0xFFFFFC00u) | ci;
        unsigned k2 = (__float_as_uint(ac2[i]) & 0xFFFFFC00u) | ci;
        unsigned k3 = (__float_as_uint(ac3[i]) & 0xFFFFFC00u) | ci;
        best[i]      = umax32(best[i],      k0);
        best[4 + i]  = umax32(best[4 + i],  k1);
        best[8 + i]  = umax32(best[8 + i],  k2);
        best[12 + i] = umax32(best[12 + i], k3);
    }
}

// K-loop over 16 chunks. B0 must hold chunk 0 on entry; wrap re-read leaves
// B0 holding chunk 0 again on exit (free prefetch for the next tile).
__device__ __forceinline__ void vq_kloop(const long long (&a)[4][8], unsigned (&best)[16],
                                         const char* bbase, const float* ep, int colinv0,
                                         i32x4 (&B0)[4], i32x4 (&B1)[4]) {
    for (int c = 0; c < 16; c += 2) {
        vq_step(a, best, bbase, ep, colinv0, B0, B1, c, c + 1);
        vq_step(a, best, bbase, ep, colinv0, B1, B0, c + 1, (c + 2) & 15);
    }
}

// Cross-lane + cross-wave argmin reduce, loss contribution, gather + NT store.
__device__ __forceinline__ void vq_reduce_store(unsigned (&best)[16],
        int tid, int cg, int q, int ln, int b0,
        unsigned* ur_s, int* idx_s, const float* zsq_row,
        const float* __restrict__ cb, float* __restrict__ out) {
    #pragma unroll
    for (int m = 1; m < 16; m <<= 1)
        #pragma unroll
        for (int i = 0; i < 16; ++i)
            best[i] = umax32(best[i], (unsigned)__shfl_xor((int)best[i], m));

    if (ln == 0) {
        #pragma unroll
        for (int rf = 0; rf < 4; ++rf) {
            u32x4 v = {best[rf * 4 + 0], best[rf * 4 + 1],
                       best[rf * 4 + 2], best[rf * 4 + 3]};
            *(u32x4*)(ur_s + cg * 64 + rf * 16 + q * 4) = v;   // rows rf*16+q*4+i
        }
    }
    __syncthreads();

    if (tid < 64) {
        unsigned u = umax32(umax32(ur_s[tid], ur_s[64 + tid]),
                            umax32(ur_s[128 + tid], ur_s[192 + tid]));
        int k = 1023 - (int)(u & 1023u);
        // midpoint-reconstruct the truncated score: s+64
        float sval = __uint_as_float((u & 0xFFFFFC00u) | 0x200u) - 64.0f;
        idx_s[tid] = k;
        // row loss: ||z-e*||^2 = ||z||^2 - s/256
        float lsum = zsq_row[tid] - sval * 0.00390625f;
        #pragma unroll
        for (int off = 32; off; off >>= 1) lsum += __shfl_down(lsum, off);
        if (tid == 0) atomicAdd(out + ND, lsum * (1.0f / (float)ND));
    }
    __syncthreads();

    // gather + non-temporal store (drains under the next tile's K-loop)
    #pragma unroll
    for (int i = 0; i < 16; ++i) {
        int item = tid + i * 256;
        int row = item >> 6, c4 = item & 63;
        int k = idx_s[row];
        f32x4 v = *(const f32x4*)(cb + (size_t)k * DDIM + c4 * 4);
        __builtin_nontemporal_store(v, (f32x4*)(out + (size_t)(b0 + row) * DDIM + c4 * 4));
    }
}

// ---------------- Main: persistent 2-tile pipeline ---------------------------
// 512 blocks x 256 thr (4 waves = col groups of 256). Each block: tiles b, b+512.
// Pipeline: tile1 z-loads issue BEFORE tile0's K-loop (in flight underneath);
// tile0's NT stores issue before tile1's pack (drain under tile1's K-loop).
// B chunk-0 for tile1 comes free from the K-loop's wrap re-read.
__global__ __launch_bounds__(256, 2) void vq_main_kernel(const float* __restrict__ z,
                                                         const float* __restrict__ cb,
                                                         const char* __restrict__ cbf,
                                                         const float* __restrict__ esq_scaled,
                                                         float* __restrict__ out) {
    __shared__ long long A0[2048];      // 16 KB tile0 fragments
    __shared__ long long A1[2048];      // 16 KB tile1 fragments
    __shared__ float esq_s[KCB];        // 4 KB: 64 - 256*||e||^2
    __shared__ float zsq_s[2][64];
    __shared__ unsigned ur_s[256];      // [cg][row] packed keys
    __shared__ int idx_s[64];

    const int tid  = threadIdx.x;
    const int cg   = tid >> 6;          // wave id = column group (cols cg*256..)
    const int lane = tid & 63;
    const int q    = lane >> 4;
    const int ln   = lane & 15;
    // pack mapping: thread (r, t) owns row r, cols t*64..t*64+63
    const int r = tid >> 2, t = tid & 3;
    const int mm = r & 15;
    const int fb = (r >> 4) * 8 + 2 * t;       // frag base (s in {0,1} added)
    const int b0 = blockIdx.x * 64;
    const int b1 = b0 + NBLK * 64;

    #pragma unroll
    for (int i = 0; i < 4; ++i) {
        int ix = tid + i * 256;
        esq_s[ix] = 64.0f - esq_scaled[ix];   // bias +64 folded in, negated
    }

    // early B prefetch for chunk 0 (L2-resident after first touch)
    const char* bbase = cbf + (size_t)cg * 65536 + lane * 16;
    i32x4 B0[4], B1[4];
    #pragma unroll
    for (int kp = 0; kp < 4; ++kp)
        B0[kp] = *(const i32x4*)(bbase + kp * 1024);

    // ---- tile0: load z, pack to A0 ----------------------------------------
    {
        const float* zp = z + (size_t)(b0 + r) * DDIM + t * 64;
        f32x4 v[16];
        #pragma unroll
        for (int i = 0; i < 16; ++i) v[i] = *(const f32x4*)(zp + i * 4);
        float sq = pack8(v, A0, fb, mm) + pack8(v + 8, A0, fb + 1, mm);
        sq += __shfl_xor(sq, 1);
        sq += __shfl_xor(sq, 2);               // row sum over the 4 t-lanes
        if (t == 0) zsq_s[0][r] = sq;
    }
    __syncthreads();

    long long a[4][8];
    #pragma unroll
    for (int rf = 0; rf < 4; ++rf)
        #pragma unroll
        for (int ks = 0; ks < 8; ++ks)
            a[rf][ks] = A0[(rf * 8 + ks) * 64 + lane];

    // ---- issue tile1 z loads now; they fly under tile0's K-loop -----------
    f32x4 zb[16];
    {
        const float* zp = z + (size_t)(b1 + r) * DDIM + t * 64;
        #pragma unroll
        for (int i = 0; i < 16; ++i) zb[i] = *(const f32x4*)(zp + i * 4);
    }

    unsigned best[16];
    #pragma unroll
    for (int i = 0; i < 16; ++i) best[i] = 0u;
    const float* ep = esq_s + cg * 256 + ln;
    const int colinv0 = 1023 - cg * 256 - ln;

    vq_kloop(a, best, bbase, ep, colinv0, B0, B1);
    vq_reduce_store(best, tid, cg, q, ln, b0, ur_s, idx_s, zsq_s[0], cb, out);

    // ---- tile1: pack (zb resident by now), reload frags, go again ---------
    {
        float sq = pack8(zb, A1, fb, mm) + pack8(zb + 8, A1, fb + 1, mm);
        sq += __shfl_xor(sq, 1);
        sq += __shfl_xor(sq, 2);
        if (t == 0) zsq_s[1][r] = sq;
    }
    __syncthreads();

    #pragma unroll
    for (int rf = 0; rf < 4; ++rf)
        #pragma unroll
        for (int ks = 0; ks < 8; ++ks)
            a[rf][ks] = A1[(rf * 8 + ks) * 64 + lane];

    #pragma unroll
    for (int i = 0; i < 16; ++i) best[i] = 0u;

    // B0 holds chunk 0 from the wrap re-read of tile0's K-loop
    vq_kloop(a, best, bbase, ep, colinv0, B0, B1);
    vq_reduce_store(best, tid, cg, q, ln, b1, ur_s, idx_s, zsq_s[1], cb, out);
}

extern "C" void kernel_launch(void* const* d_in, const int* in_sizes, int n_in,
                              void* d_out, int out_size, void* d_ws, size_t ws_size,
                              hipStream_t stream) {
    const float* z  = (const float*)d_in[0];   // z_e, 65536 x 256 fp32
    const float* cb = (const float*)d_in[1];   // codebook, 1024 x 256 fp32
    float* out = (float*)d_out;                // z_q (16777216) ++ loss (1)

    float* esq_scaled = (float*)d_ws;                    // 4 KB
    char*  cb_frag    = (char*)d_ws + 4096;              // 256 KB fp8 fragments

    vq_prep_kernel<<<128, 256, 0, stream>>>(cb, cb_frag, esq_scaled, out + ND);
    vq_main_kernel<<<NBLK, 256, 0, stream>>>(z, cb, cb_frag, esq_scaled, out);
}